// Round 1
// baseline (206.700 us; speedup 1.0000x reference)
//
#include <hip/hip_runtime.h>

#define DIM 32
#define BATCH 65536
#define MATS_PER_BLOCK 8
#define NBLOCKS (BATCH / MATS_PER_BLOCK)   // 8192

// ---------------- Kernel A: sigma = C_ @ inv(B_ + C_) ----------------
// lam = B_ @ inv(C_) + I = (B_ + C_) @ inv(C_)  =>  sigma = inv(lam) = C_ @ inv(B_ + C_)
__global__ __launch_bounds__(1024) void sigma_kernel(const float* __restrict__ B,
                                                     const float* __restrict__ C,
                                                     float* __restrict__ sigma_out) {
    __shared__ float Bs[DIM][DIM + 1];
    __shared__ float Cs[DIM][DIM + 1];
    __shared__ float Aug[DIM][2 * DIM + 1];
    __shared__ float rowk[2 * DIM];
    __shared__ float colk[DIM];
    const int tid = threadIdx.x;
    const int i = tid >> 5;
    const int j = tid & 31;

    // load + relu the diagonal
    float b = B[i * DIM + j];
    float c = C[i * DIM + j];
    if (i == j) { b = fmaxf(b, 0.0f); c = fmaxf(c, 0.0f); }
    Bs[i][j] = b;
    Cs[i][j] = c;
    __syncthreads();

    // diag <- row-sum of abs (diagonally dominant)
    if (j == 0) {
        float sb = 0.0f, sc = 0.0f;
        for (int t = 0; t < DIM; ++t) { sb += fabsf(Bs[i][t]); sc += fabsf(Cs[i][t]); }
        Bs[i][i] = sb;
        Cs[i][i] = sc;
    }
    __syncthreads();

    // Aug = [B_ + C_ | I]
    Aug[i][j] = Bs[i][j] + Cs[i][j];
    Aug[i][DIM + j] = (i == j) ? 1.0f : 0.0f;
    __syncthreads();

    // Gauss-Jordan (no pivoting: matrix is diagonally dominant, diag > 0)
    for (int k = 0; k < DIM; ++k) {
        if (tid < 2 * DIM) rowk[tid] = Aug[k][tid];
        else if (tid < 3 * DIM) colk[tid - 2 * DIM] = Aug[tid - 2 * DIM][k];
        __syncthreads();
        const float piv = rowk[k];
        if (i == k) {
            Aug[i][j]       = rowk[j] / piv;
            Aug[i][DIM + j] = rowk[DIM + j] / piv;
        } else {
            const float f = colk[i] / piv;
            Aug[i][j]       -= f * rowk[j];
            Aug[i][DIM + j] -= f * rowk[DIM + j];
        }
        __syncthreads();
    }

    // sigma = Cs @ Minv  (Minv = right half of Aug)
    float s = 0.0f;
    for (int t = 0; t < DIM; ++t) s += Cs[i][t] * Aug[t][DIM + j];
    sigma_out[i * DIM + j] = s;
}

// ---------------- Kernel B: per-element 32x32 determinant (LU, no pivoting) ----------------
// Column-per-lane: each 32-lane group owns one matrix; lane j holds column j in registers.
// A wave64 processes 2 matrices in lockstep (identical control flow, no divergence).
__global__ __launch_bounds__(256) void det_kernel(const int* __restrict__ x,
                                                  const float* __restrict__ sigma_g,
                                                  float* __restrict__ partial) {
    __shared__ float sig[DIM][DIM];
    __shared__ float gsum[MATS_PER_BLOCK];
    const int tid = threadIdx.x;

    for (int idx = tid; idx < DIM * DIM; idx += 256)
        sig[idx >> 5][idx & 31] = sigma_g[idx];
    __syncthreads();

    const int group = tid >> 5;   // 0..7  (matrix within block)
    const int col = tid & 31;     // this lane's column
    const int mat = blockIdx.x * MATS_PER_BLOCK + group;

    const int xv = x[mat * DIM + col];
    const float sgn = xv ? 1.0f : -1.0f;
    const float sd = sig[col][col];
    const float dval = xv ? sd : (1.0f - sd);

    // build column: m[i][col] = sigma[i][col]*sgn (i != col), m[col][col] = dval
    float a[DIM];
#pragma unroll
    for (int i2 = 0; i2 < DIM; ++i2) {
        const float v = sig[i2][col] * sgn;
        a[i2] = (i2 == col) ? dval : v;   // i2 compile-time, col runtime -> cndmask
    }

    // LU without pivoting; det = product of pivots
    float prod = 1.0f;
#pragma unroll
    for (int k = 0; k < DIM; ++k) {
        const float piv = __shfl(a[k], k, 32);   // broadcast pivot m[k][k]
        prod *= piv;
        const float invp = 1.0f / piv;           // uniform within group
        const float w = a[k] * invp;             // lane-local u_c / piv
#pragma unroll
        for (int i2 = k + 1; i2 < DIM; ++i2) {
            const float l = __shfl(a[i2], k, 32);  // raw m[i2][k] from lane k
            a[i2] = fmaf(-l, w, a[i2]);
        }
    }

    const float logdet = logf(prod);   // det > 0 (diagonally dominant, positive diag)

    if (col == 0) gsum[group] = logdet;
    __syncthreads();
    if (tid == 0) {
        float s = 0.0f;
#pragma unroll
        for (int g = 0; g < MATS_PER_BLOCK; ++g) s += gsum[g];
        partial[blockIdx.x] = s;
    }
}

// ---------------- Kernel C: deterministic final reduction (double accum) ----------------
__global__ __launch_bounds__(256) void reduce_kernel(const float* __restrict__ partial,
                                                     float* __restrict__ out) {
    __shared__ double sd[256];
    const int tid = threadIdx.x;
    double s = 0.0;
    for (int idx = tid; idx < NBLOCKS; idx += 256) s += (double)partial[idx];
    sd[tid] = s;
    __syncthreads();
    for (int off = 128; off > 0; off >>= 1) {
        if (tid < off) sd[tid] += sd[tid + off];
        __syncthreads();
    }
    if (tid == 0) out[0] = (float)(sd[0] / (double)BATCH);
}

extern "C" void kernel_launch(void* const* d_in, const int* in_sizes, int n_in,
                              void* d_out, int out_size, void* d_ws, size_t ws_size,
                              hipStream_t stream) {
    const int* x = (const int*)d_in[0];
    const float* B = (const float*)d_in[1];
    const float* C = (const float*)d_in[2];

    float* sigma = (float*)d_ws;                 // 1024 floats
    float* partial = sigma + DIM * DIM;          // 8192 floats
    float* out = (float*)d_out;

    sigma_kernel<<<1, 1024, 0, stream>>>(B, C, sigma);
    det_kernel<<<NBLOCKS, 256, 0, stream>>>(x, sigma, partial);
    reduce_kernel<<<1, 256, 0, stream>>>(partial, out);
}

// Round 2
// 143.194 us; speedup vs baseline: 1.4435x; 1.4435x over previous
//
#include <hip/hip_runtime.h>

#define DIM 32
#define BATCH 65536
#define MATS_PER_BLOCK 8
#define NBLOCKS (BATCH / MATS_PER_BLOCK)   // 8192

// ---------------- Kernel A ----------------
// Stabilize B,C -> B_, C_.  G = B_ @ inv(C_)  (= sigma^{-1} - I).
// log det sigma = -log det(G + I).  Outputs: G (32x32) and s0 = logdet(sigma).
__global__ __launch_bounds__(1024) void sigma_kernel(const float* __restrict__ B,
                                                     const float* __restrict__ C,
                                                     float* __restrict__ G_out,
                                                     float* __restrict__ s0_out) {
    __shared__ float Bs[DIM][DIM + 1];
    __shared__ float Cs[DIM][DIM + 1];
    __shared__ float Aug[DIM][2 * DIM + 1];
    __shared__ float rowk[2 * DIM];
    __shared__ float colk[DIM];
    const int tid = threadIdx.x;
    const int i = tid >> 5;
    const int j = tid & 31;

    // load + relu diagonal
    float b = B[i * DIM + j];
    float c = C[i * DIM + j];
    if (i == j) { b = fmaxf(b, 0.0f); c = fmaxf(c, 0.0f); }
    Bs[i][j] = b;
    Cs[i][j] = c;
    __syncthreads();

    // diag <- row abs-sum (diagonally dominant)
    if (j == 0) {
        float sb = 0.0f, sc = 0.0f;
        for (int t = 0; t < DIM; ++t) { sb += fabsf(Bs[i][t]); sc += fabsf(Cs[i][t]); }
        Bs[i][i] = sb;
        Cs[i][i] = sc;
    }
    __syncthreads();

    // invert C_ via Gauss-Jordan: Aug = [C_ | I]
    Aug[i][j] = Cs[i][j];
    Aug[i][DIM + j] = (i == j) ? 1.0f : 0.0f;
    __syncthreads();
    for (int k = 0; k < DIM; ++k) {
        if (tid < 2 * DIM) rowk[tid] = Aug[k][tid];
        else if (tid < 3 * DIM) colk[tid - 2 * DIM] = Aug[tid - 2 * DIM][k];
        __syncthreads();
        const float piv = rowk[k];
        if (i == k) {
            Aug[i][j]       = rowk[j] / piv;
            Aug[i][DIM + j] = rowk[DIM + j] / piv;
        } else {
            const float f = colk[i] / piv;
            Aug[i][j]       -= f * rowk[j];
            Aug[i][DIM + j] -= f * rowk[DIM + j];
        }
        __syncthreads();
    }

    // G = B_ @ inv(C_)
    float g = 0.0f;
    for (int t = 0; t < DIM; ++t) g += Bs[i][t] * Aug[t][DIM + j];
    G_out[i * DIM + j] = g;
    __syncthreads();

    // M = G + I into Cs; det via Gauss-Jordan pivots (diag dominant, no pivoting)
    Cs[i][j] = g + ((i == j) ? 1.0f : 0.0f);
    __syncthreads();
    float acc = 0.0f;
    for (int k = 0; k < DIM; ++k) {
        if (tid < DIM) rowk[tid] = Cs[k][tid];
        else if (tid < 2 * DIM) colk[tid - DIM] = Cs[tid - DIM][k];
        __syncthreads();
        const float piv = rowk[k];
        acc += logf(piv);   // uniform across threads
        if (i == k) Cs[i][j] = rowk[j] / piv;
        else        Cs[i][j] -= colk[i] / piv * rowk[j];
        __syncthreads();
    }
    if (tid == 0) s0_out[0] = -acc;   // log det sigma
}

// ---------------- Kernel B: det of G[Q,Q] (|Q| = #zeros of x-row) ----------------
// Column-per-lane LU on the identity-padded submatrix. Uniform guards (k<nmax,
// i2<nmax) compile to scalar branches -> shuffles beyond nmax are truly skipped.
__global__ __launch_bounds__(256) void det_kernel(const int* __restrict__ x,
                                                  const float* __restrict__ G_g,
                                                  float* __restrict__ partial) {
    __shared__ float G[DIM * DIM];
    __shared__ float gsum[MATS_PER_BLOCK];
    const int tid = threadIdx.x;

    for (int idx = tid; idx < DIM * DIM; idx += 256) G[idx] = G_g[idx];
    __syncthreads();

    const int group = tid >> 5;
    const int col = tid & 31;
    const int mat = blockIdx.x * MATS_PER_BLOCK + group;

    const int xv = x[mat * DIM + col];
    const unsigned long long ball = __ballot(xv == 0);
    const unsigned mask = (unsigned)(ball >> (tid & 32));   // this group's Q-mask
    const int n = __popc(mask);
    const int nOther = __shfl_xor(n, 32);                    // other half-wave's n
    const int nmax = (n > nOther) ? n : nOther;

    // jc = col-th set bit of mask (clamped when col >= n)
    unsigned u = mask;
#pragma unroll
    for (int t = 0; t < 31; ++t)
        if (t < col) u &= (u - 1);
    const int jc = (__ffs((int)u) - 1) & 31;

    // identity-init (padding region stays exact), then gather G[Q,Q]
    float a[DIM];
#pragma unroll
    for (int r = 0; r < DIM; ++r) a[r] = (r == col) ? 1.0f : 0.0f;
    unsigned u2 = mask;
#pragma unroll
    for (int r = 0; r < DIM; ++r) {
        if (r < n) {
            const int ir = __ffs((int)u2) - 1;
            u2 &= (u2 - 1);
            a[r] = G[ir * DIM + jc];
        }
    }

    // LU without pivoting on the first nmax rows/cols; det = prod of first n pivots
    float prod = 1.0f;
#pragma unroll
    for (int k = 0; k < DIM; ++k) {
        if (k < nmax) {
            const float piv = __shfl(a[k], k, 32);
            if (k < n) prod *= piv;
            const float invp = 1.0f / piv;
            const float w = a[k] * invp;
#pragma unroll
            for (int i2 = k + 1; i2 < DIM; ++i2) {
                if (i2 < nmax) {
                    const float l = __shfl(a[i2], k, 32);
                    a[i2] = fmaf(-l, w, a[i2]);
                }
            }
        }
    }

    const float logdet = logf(prod);   // G[Q,Q] ~ I: det > 0

    if (col == 0) gsum[group] = logdet;
    __syncthreads();
    if (tid == 0) {
        float s = 0.0f;
#pragma unroll
        for (int g = 0; g < MATS_PER_BLOCK; ++g) s += gsum[g];
        partial[blockIdx.x] = s;
    }
}

// ---------------- Kernel C: deterministic final reduction ----------------
__global__ __launch_bounds__(256) void reduce_kernel(const float* __restrict__ partial,
                                                     const float* __restrict__ s0,
                                                     float* __restrict__ out) {
    __shared__ double sd[256];
    const int tid = threadIdx.x;
    double s = 0.0;
    for (int idx = tid; idx < NBLOCKS; idx += 256) s += (double)partial[idx];
    sd[tid] = s;
    __syncthreads();
    for (int off = 128; off > 0; off >>= 1) {
        if (tid < off) sd[tid] += sd[tid + off];
        __syncthreads();
    }
    if (tid == 0) out[0] = s0[0] + (float)(sd[0] / (double)BATCH);
}

extern "C" void kernel_launch(void* const* d_in, const int* in_sizes, int n_in,
                              void* d_out, int out_size, void* d_ws, size_t ws_size,
                              hipStream_t stream) {
    const int* x = (const int*)d_in[0];
    const float* B = (const float*)d_in[1];
    const float* C = (const float*)d_in[2];

    float* G = (float*)d_ws;                   // 1024 floats
    float* s0 = G + DIM * DIM;                 // 1 float
    float* partial = G + DIM * DIM + 32;       // 8192 floats
    float* out = (float*)d_out;

    sigma_kernel<<<1, 1024, 0, stream>>>(B, C, G, s0);
    det_kernel<<<NBLOCKS, 256, 0, stream>>>(x, G, partial);
    reduce_kernel<<<1, 256, 0, stream>>>(partial, s0, out);
}

// Round 3
// 61.883 us; speedup vs baseline: 3.3402x; 2.3140x over previous
//
#include <hip/hip_runtime.h>

#define DIM 32
#define BATCH 65536
#define DET_BLOCKS 2048
// per block: 256 thr = 4 waves, 2 matrices/wave/iter = 8 mats/iter, 4 iters = 32 mats

// ---------------- Kernel A: prep ----------------
// Stabilize B,C.  G = B_ @ inv(C_) (= sigma^{-1} - I).
// Outputs: Ph[i][j] = 0.5*(g_ij/g_ii)*(g_ji/g_jj) (zero diag), c[i] = log g_ii,
//          s0 = log det sigma = -log det(G + I).
__global__ __launch_bounds__(256) void prep_kernel(const float* __restrict__ B,
                                                   const float* __restrict__ C,
                                                   float* __restrict__ Ph_out,
                                                   float* __restrict__ c_out,
                                                   float* __restrict__ s0_out) {
    __shared__ float Bs[DIM][DIM + 1];
    __shared__ float Cs[DIM][DIM + 1];
    __shared__ float Gs[DIM][DIM + 1];
    __shared__ float Aug[DIM][2 * DIM + 1];
    __shared__ float rowk[2 * DIM];
    __shared__ float colk[DIM];
    const int tid = threadIdx.x;
    const int j = tid & 31;
    const int r = tid >> 5;   // 0..7; thread handles rows r, r+8, r+16, r+24

    for (int t = 0; t < 4; ++t) {
        const int i = r + 8 * t;
        float b = B[i * DIM + j];
        float c = C[i * DIM + j];
        if (i == j) { b = fmaxf(b, 0.0f); c = fmaxf(c, 0.0f); }
        Bs[i][j] = b;
        Cs[i][j] = c;
    }
    __syncthreads();
    if (tid < DIM) {
        float sb = 0.0f, sc = 0.0f;
        for (int t = 0; t < DIM; ++t) { sb += fabsf(Bs[tid][t]); sc += fabsf(Cs[tid][t]); }
        Bs[tid][tid] = sb;
        Cs[tid][tid] = sc;
    }
    __syncthreads();

    // invert C_ : Aug = [C_ | I], Gauss-Jordan (diag dominant, no pivoting)
    for (int t = 0; t < 4; ++t) {
        const int i = r + 8 * t;
        Aug[i][j] = Cs[i][j];
        Aug[i][DIM + j] = (i == j) ? 1.0f : 0.0f;
    }
    __syncthreads();
    for (int k = 0; k < DIM; ++k) {
        if (tid < 2 * DIM) rowk[tid] = Aug[k][tid];
        else if (tid < 3 * DIM) colk[tid - 2 * DIM] = Aug[tid - 2 * DIM][k];
        __syncthreads();
        const float piv = rowk[k];
        for (int t = 0; t < 4; ++t) {
            const int i = r + 8 * t;
            if (i == k) {
                Aug[i][j]       = rowk[j] / piv;
                Aug[i][DIM + j] = rowk[DIM + j] / piv;
            } else {
                const float f = colk[i] / piv;
                Aug[i][j]       -= f * rowk[j];
                Aug[i][DIM + j] -= f * rowk[DIM + j];
            }
        }
        __syncthreads();
    }

    // G = B_ @ inv(C_)
    for (int t = 0; t < 4; ++t) {
        const int i = r + 8 * t;
        float g = 0.0f;
        for (int u = 0; u < DIM; ++u) g += Bs[i][u] * Aug[u][DIM + j];
        Gs[i][j] = g;
    }
    __syncthreads();

    // Ph and c
    for (int t = 0; t < 4; ++t) {
        const int i = r + 8 * t;
        const float ph = (i == j) ? 0.0f
                         : 0.5f * (Gs[i][j] * Gs[j][i]) / (Gs[i][i] * Gs[j][j]);
        Ph_out[i * DIM + j] = ph;
    }
    if (tid < DIM) c_out[tid] = logf(Gs[tid][tid]);

    // s0 = -log det(G + I) via Gauss-Jordan pivots on M = G + I (in Cs)
    for (int t = 0; t < 4; ++t) {
        const int i = r + 8 * t;
        Cs[i][j] = Gs[i][j] + ((i == j) ? 1.0f : 0.0f);
    }
    __syncthreads();
    float acc = 0.0f;
    for (int k = 0; k < DIM; ++k) {
        if (tid < DIM) rowk[tid] = Cs[k][tid];
        else if (tid < 2 * DIM) colk[tid - DIM] = Cs[tid - DIM][k];
        __syncthreads();
        const float piv = rowk[k];
        acc += logf(piv);   // uniform
        for (int t = 0; t < 4; ++t) {
            const int i = r + 8 * t;
            if (i == k) Cs[i][j] = rowk[j] / piv;
            else        Cs[i][j] -= colk[i] / piv * rowk[j];
        }
        __syncthreads();
    }
    if (tid == 0) s0_out[0] = -acc;
}

// ---------------- Kernel B: logdet(G[Q,Q]) ~= s.c - s^T Ph s ----------------
// Row-per-lane: lane (tid&31) owns row i; Ph row lives in 32 VGPRs for the
// whole kernel. Per matrix: ballot -> 32-bit mask s; q_i = sum_j s_j Ph[i][j]
// (32 predicated adds, no shuffles); contribution s_i*(c_i - q_i) accumulates
// per-lane across matrices; single cross-lane reduction at the end.
__global__ __launch_bounds__(256) void det_kernel(const int* __restrict__ x,
                                                  const float* __restrict__ Ph_g,
                                                  const float* __restrict__ c_g,
                                                  float* __restrict__ partial) {
    __shared__ float Pl[DIM][DIM + 1];
    __shared__ float cl[DIM];
    __shared__ float wsum[4];
    const int tid = threadIdx.x;

    for (int idx = tid; idx < DIM * DIM; idx += 256)
        Pl[idx >> 5][idx & 31] = Ph_g[idx];
    if (tid < DIM) cl[tid] = c_g[tid];
    __syncthreads();

    const int i = tid & 31;       // row owned by this lane
    float p[DIM];
#pragma unroll
    for (int jj = 0; jj < DIM; ++jj) p[jj] = Pl[i][jj];
    const float ci = cl[i];

    const int lane = tid & 63;
    const int wave = tid >> 6;    // 0..3
    const int matsPerBlock = BATCH / DET_BLOCKS;   // 32
    const int base = blockIdx.x * matsPerBlock;

    float psum = 0.0f;
    for (int it = 0; it < matsPerBlock / 8; ++it) {       // 4 iterations
        const int matPair = base + it * 8 + wave * 2;     // 2 mats per wave
        const int xv = x[matPair * DIM + lane];           // coalesced 256B/wave
        const unsigned long long ball = __ballot(xv == 0);
        const unsigned mask = (unsigned)(ball >> (lane & 32));   // this half's Q

        float q = 0.0f;
#pragma unroll
        for (int jj = 0; jj < DIM; ++jj)
            q += ((mask >> jj) & 1u) ? p[jj] : 0.0f;

        psum += ((mask >> i) & 1u) ? (ci - q) : 0.0f;
    }

    // reduce psum over the wave (both halves belong in the block total)
#pragma unroll
    for (int off = 1; off < 64; off <<= 1)
        psum += __shfl_xor(psum, off, 64);
    if (lane == 0) wsum[wave] = psum;
    __syncthreads();
    if (tid == 0)
        partial[blockIdx.x] = wsum[0] + wsum[1] + wsum[2] + wsum[3];
}

// ---------------- Kernel C: deterministic final reduction ----------------
__global__ __launch_bounds__(256) void reduce_kernel(const float* __restrict__ partial,
                                                     const float* __restrict__ s0,
                                                     float* __restrict__ out) {
    __shared__ double sd[256];
    const int tid = threadIdx.x;
    double s = 0.0;
    for (int idx = tid; idx < DET_BLOCKS; idx += 256) s += (double)partial[idx];
    sd[tid] = s;
    __syncthreads();
    for (int off = 128; off > 0; off >>= 1) {
        if (tid < off) sd[tid] += sd[tid + off];
        __syncthreads();
    }
    if (tid == 0) out[0] = s0[0] + (float)(sd[0] / (double)BATCH);
}

extern "C" void kernel_launch(void* const* d_in, const int* in_sizes, int n_in,
                              void* d_out, int out_size, void* d_ws, size_t ws_size,
                              hipStream_t stream) {
    const int* x = (const int*)d_in[0];
    const float* B = (const float*)d_in[1];
    const float* C = (const float*)d_in[2];

    float* Ph = (float*)d_ws;                    // 1024 floats
    float* c = Ph + DIM * DIM;                   // 32 floats
    float* s0 = c + DIM;                         // 1 float (+31 pad)
    float* partial = s0 + 32;                    // 2048 floats
    float* out = (float*)d_out;

    prep_kernel<<<1, 256, 0, stream>>>(B, C, Ph, c, s0);
    det_kernel<<<DET_BLOCKS, 256, 0, stream>>>(x, Ph, c, partial);
    reduce_kernel<<<1, 256, 0, stream>>>(partial, s0, out);
}

// Round 4
// 35.652 us; speedup vs baseline: 5.7977x; 1.7357x over previous
//
#include <hip/hip_runtime.h>

#define DIM 32
#define BATCH 65536
#define DET_BLOCKS 2048

// ---------------- Kernel A: prep (single-wave GJ, barrier-free) ----------------
// Stabilize B,C -> B_, C_.  G^T = inv(C_^T) B_^T via Gauss-Jordan on [C_^T | B_^T]
// held column-per-lane in ONE wave64 (lane j<32: C_ row j; lane 32+i: B_ row i).
// After elimination lane 32+i holds G row i.  s0 = logdet(C_) - logdet(B_+C_).
// Outputs: Ph[i][j] = 0.5*g_ij*g_ji/(g_ii*g_jj) (zero diag), c[i]=log g_ii, s0.
__global__ __launch_bounds__(256) void prep_kernel(const float* __restrict__ B,
                                                   const float* __restrict__ C,
                                                   float* __restrict__ Ph_out,
                                                   float* __restrict__ c_out,
                                                   float* __restrict__ s0_out) {
    __shared__ float Gs[DIM][DIM + 1];
    const int tid = threadIdx.x;
    const int wave = tid >> 6;
    const int lane = tid & 63;

    if (wave == 0) {
        const int r = lane & 31;                       // my row index
        const float* src = (lane < 32) ? C : B;        // low half: C_, high half: B_

        // ---- load my row + stabilize (all lane-local) ----
        float a[DIM];
#pragma unroll
        for (int t = 0; t < DIM; ++t) a[t] = src[r * DIM + t];
        float rsum = 0.0f;
#pragma unroll
        for (int t = 0; t < DIM; ++t) {
            const float v = (t == r) ? fmaxf(a[t], 0.0f) : a[t];   // relu diag
            a[t] = v;
            rsum += fabsf(v);
        }
#pragma unroll
        for (int t = 0; t < DIM; ++t) a[t] = (t == r) ? rsum : a[t];  // diag <- abs rowsum

        // ---- (B_+C_) row r: swap halves and add ----
        float bc[DIM];
#pragma unroll
        for (int t = 0; t < DIM; ++t) bc[t] = a[t] + __shfl_xor(a[t], 32, 64);

        // ---- Gauss-Jordan on [C_^T | B_^T]: lane l holds column l ----
        // Rows 0..31; pivot M[k][k] lives in lane k's a[k].
        float prodC = 1.0f;
#pragma unroll
        for (int k = 0; k < DIM; ++k) {
            const float piv = __shfl(a[k], k, 64);
            prodC *= piv;
            const float invp = 1.0f / piv;
            a[k] *= invp;                               // normalize row k
#pragma unroll
            for (int t = 0; t < DIM; ++t) {
                if (t != k) {
                    const float f = __shfl(a[t], k, 64);   // factor M[t][k] (pre-update)
                    a[t] = fmaf(-f, a[k], a[t]);
                }
            }
        }
        // lanes 32..63 now hold G rows: lane 32+i has G[i][0..31] in a[]

        // ---- LU (det only) of B_+C_ (all lanes mirror-redundant; lanes 0-31 valid) ----
        float prodBC = 1.0f;
#pragma unroll
        for (int k = 0; k < DIM; ++k) {
            const float piv = __shfl(bc[k], k, 64);
            prodBC *= piv;
            const float w = bc[k] * (1.0f / piv);
#pragma unroll
            for (int t = k + 1; t < DIM; ++t) {
                const float f = __shfl(bc[t], k, 64);
                bc[t] = fmaf(-f, w, bc[t]);
            }
        }

        // ---- publish ----
        if (lane >= 32) {
            const int i = lane - 32;
#pragma unroll
            for (int t = 0; t < DIM; ++t) Gs[i][t] = a[t];
        }
        if (lane == 0) s0_out[0] = logf(prodC) - logf(prodBC);
    }
    __syncthreads();

    // ---- Ph and c from G (all 256 threads) ----
#pragma unroll
    for (int q = 0; q < 4; ++q) {
        const int idx = tid + 256 * q;        // 0..1023
        const int i = idx >> 5, j = idx & 31;
        const float gij = Gs[i][j], gji = Gs[j][i];
        const float gii = Gs[i][i], gjj = Gs[j][j];
        Ph_out[idx] = (i == j) ? 0.0f : 0.5f * (gij * gji) / (gii * gjj);
    }
    if (tid < DIM) c_out[tid] = logf(Gs[tid][tid]);
}

// ---------------- Kernel B: logdet(G[Q,Q]) ~= s.c - s^T Ph s ----------------
__global__ __launch_bounds__(256) void det_kernel(const int* __restrict__ x,
                                                  const float* __restrict__ Ph_g,
                                                  const float* __restrict__ c_g,
                                                  float* __restrict__ partial) {
    __shared__ float Pl[DIM][DIM + 1];
    __shared__ float cl[DIM];
    __shared__ float wsum[4];
    const int tid = threadIdx.x;

    for (int idx = tid; idx < DIM * DIM; idx += 256)
        Pl[idx >> 5][idx & 31] = Ph_g[idx];
    if (tid < DIM) cl[tid] = c_g[tid];
    __syncthreads();

    const int i = tid & 31;       // row owned by this lane
    float p[DIM];
#pragma unroll
    for (int jj = 0; jj < DIM; ++jj) p[jj] = Pl[i][jj];
    const float ci = cl[i];

    const int lane = tid & 63;
    const int wave = tid >> 6;    // 0..3
    const int matsPerBlock = BATCH / DET_BLOCKS;   // 32
    const int base = blockIdx.x * matsPerBlock;

    float psum = 0.0f;
    for (int it = 0; it < matsPerBlock / 8; ++it) {       // 4 iterations
        const int matPair = base + it * 8 + wave * 2;     // 2 mats per wave
        const int xv = x[matPair * DIM + lane];           // coalesced 256B/wave
        const unsigned long long ball = __ballot(xv == 0);
        const unsigned mask = (unsigned)(ball >> (lane & 32));   // this half's Q

        float q = 0.0f;
#pragma unroll
        for (int jj = 0; jj < DIM; ++jj)
            q += ((mask >> jj) & 1u) ? p[jj] : 0.0f;

        psum += ((mask >> i) & 1u) ? (ci - q) : 0.0f;
    }

#pragma unroll
    for (int off = 1; off < 64; off <<= 1)
        psum += __shfl_xor(psum, off, 64);
    if (lane == 0) wsum[wave] = psum;
    __syncthreads();
    if (tid == 0)
        partial[blockIdx.x] = wsum[0] + wsum[1] + wsum[2] + wsum[3];
}

// ---------------- Kernel C: deterministic final reduction ----------------
__global__ __launch_bounds__(256) void reduce_kernel(const float* __restrict__ partial,
                                                     const float* __restrict__ s0,
                                                     float* __restrict__ out) {
    __shared__ double sd[256];
    const int tid = threadIdx.x;
    double s = 0.0;
    for (int idx = tid; idx < DET_BLOCKS; idx += 256) s += (double)partial[idx];
    sd[tid] = s;
    __syncthreads();
    for (int off = 128; off > 0; off >>= 1) {
        if (tid < off) sd[tid] += sd[tid + off];
        __syncthreads();
    }
    if (tid == 0) out[0] = s0[0] + (float)(sd[0] / (double)BATCH);
}

extern "C" void kernel_launch(void* const* d_in, const int* in_sizes, int n_in,
                              void* d_out, int out_size, void* d_ws, size_t ws_size,
                              hipStream_t stream) {
    const int* x = (const int*)d_in[0];
    const float* B = (const float*)d_in[1];
    const float* C = (const float*)d_in[2];

    float* Ph = (float*)d_ws;                    // 1024 floats
    float* c = Ph + DIM * DIM;                   // 32 floats
    float* s0 = c + DIM;                         // 1 float (+31 pad)
    float* partial = s0 + 32;                    // 2048 floats
    float* out = (float*)d_out;

    prep_kernel<<<1, 256, 0, stream>>>(B, C, Ph, c, s0);
    det_kernel<<<DET_BLOCKS, 256, 0, stream>>>(x, Ph, c, partial);
    reduce_kernel<<<1, 256, 0, stream>>>(partial, s0, out);
}